// Round 7
// baseline (374.596 us; speedup 1.0000x reference)
//
#include <hip/hip_runtime.h>

// TELIF: temporal-encoding LIF neuron scan.
// tx: [T, B, N] fp32, TE: [N, T] fp32, out ty: [T, B, N] fp32 (0/1 spikes).
// T=512, B=64, N=1024. One thread per (b,n) sequence; sequential over t.
//
// v7: WAVE CONCENTRATION -- 4 waves/SIMD instead of 1.
//   Evidence ledger: v4/v5 (reg prefetch, 256B granule, depth 1-2), v3
//   (producer wave, 1KB loads, 112KB/CU in flight), v6b (1KB granules both
//   directions, LDS transpose, depth 3) ALL land at 81-89 us, read BW
//   pinned ~1.5 TB/s logical, per-wave step time invariant at ~160 ns.
//   In-flight depth x7 and granule x4 both null => not Little's-law-limited
//   at the DRAM; the queue just grows. Every variant ran 256 blocks spread
//   over 256 CUs = 1 wave/SIMD: when the wave hits its vmcnt wait, the SIMD
//   has NO other context to issue from. fillBufferAligned at the same ~10%
//   occupancy does 6.7 TB/s -- but store-only (fire-and-forget, no stall).
//   The untested variable is waves/SIMD. Here: 64 blocks x 1024 threads =
//   16 waves/CU on 64 CUs (dispatch round-robins XCDs -> 8 blocks/XCD) =
//   4 waves/SIMD. Per-CU demand ~52 GB/s << per-CU L1 path; per-XCD
//   ~0.3 TB/s << fabric. Compute structure is verbatim v1/v4 (measured
//   best + simplest): depth-1 register prefetch, UCHUNK=16 so VGPR ~104
//   fits the 128/wave budget needed for 4 waves/SIMD co-residency.
//   If this is null too, the cap is memory-system-side at this
//   concurrency and the practical roofline is established.

#define T_STEPS 512
#define BATCH   64
#define NNEUR   1024
#define BN      (BATCH * NNEUR)
#define UCHUNK  16
#define BT      1024                 // 16 waves/block, 64 blocks on 64 CUs

__global__ __launch_bounds__(BT, 1) void telif_kernel(
    const float* __restrict__ tx, const float* __restrict__ TE,
    float* __restrict__ out)
{
    // Reference is validated against fp32 elementwise ops with a hard
    // (v > th) threshold: forbid FMA contraction so rounding matches exactly.
#pragma clang fp contract(off)

    const int flat = blockIdx.x * BT + threadIdx.x;   // b*N + n
    const int n = flat & (NNEUR - 1);

    const float* txp = tx + flat;        // stride BN along t, coalesced across lanes
    const float* tep = TE + n * T_STEPS; // contiguous along t per thread
    float*       outp = out + flat;

    float v  = 0.0f;   // REST
    float y  = 0.0f;
    float th = 0.3f;   // THRESHOLD

    float xc[UCHUNK], tc[UCHUNK];  // current chunk
    float xn[UCHUNK], tn[UCHUNK];  // next chunk (prefetch)

    // Prefetch chunk 0.
#pragma unroll
    for (int u = 0; u < UCHUNK; ++u)
        xc[u] = txp[(size_t)u * BN];
#pragma unroll
    for (int u = 0; u < UCHUNK; u += 4) {
        float4 f = *reinterpret_cast<const float4*>(tep + u);
        tc[u] = f.x; tc[u + 1] = f.y; tc[u + 2] = f.z; tc[u + 3] = f.w;
    }

#pragma unroll 1
    for (int t = 0; t < T_STEPS; t += UCHUNK) {
        const int tb = t + UCHUNK;
        if (tb < T_STEPS) {
            // Issue next chunk's loads before computing current chunk.
            // Loads precede this round's stores in program order, so the
            // rotate's implicit vmcnt wait never has to drain the stores.
#pragma unroll
            for (int u = 0; u < UCHUNK; ++u)
                xn[u] = txp[(size_t)(tb + u) * BN];
#pragma unroll
            for (int u = 0; u < UCHUNK; u += 4) {
                float4 f = *reinterpret_cast<const float4*>(tep + tb + u);
                tn[u] = f.x; tn[u + 1] = f.y; tn[u + 2] = f.z; tn[u + 3] = f.w;
            }
        }

        // Compute current chunk. Exact op order of the reference:
        //   th = th + v*te - (th - THRESHOLD)*BETA
        //   v  = v*DECAY*(1-y) + x
        //   y  = (v > th)
#pragma unroll
        for (int u = 0; u < UCHUNK; ++u) {
            float a    = v * tc[u];
            float bsum = th + a;
            float c    = th - 0.3f;
            float d    = c * 0.02f;
            th = bsum - d;
            float e  = v * 0.2f;
            float f1 = 1.0f - y;
            float g  = e * f1;
            v = g + xc[u];
            y = (v > th) ? 1.0f : 0.0f;
            __builtin_nontemporal_store(y, outp + (size_t)(t + u) * BN);
        }

        // Rotate buffers (register moves; garbage on last iter is unused).
#pragma unroll
        for (int u = 0; u < UCHUNK; ++u) { xc[u] = xn[u]; tc[u] = tn[u]; }
    }
}

extern "C" void kernel_launch(void* const* d_in, const int* in_sizes, int n_in,
                              void* d_out, int out_size, void* d_ws, size_t ws_size,
                              hipStream_t stream) {
    const float* tx = (const float*)d_in[0];  // [T, B, N]
    const float* TE = (const float*)d_in[1];  // [N, T]
    float* out = (float*)d_out;               // [T, B, N]
    telif_kernel<<<BN / BT, BT, 0, stream>>>(tx, TE, out);
}

// Round 8
// 233.632 us; speedup vs baseline: 1.6034x; 1.6034x over previous
//
#include <hip/hip_runtime.h>

// TELIF: temporal-encoding LIF neuron scan.
// tx: [T, B, N] fp32, TE: [N, T] fp32, out ty: [T, B, N] fp32 (0/1 spikes).
// T=512, B=64, N=1024. One compute thread per (b,n) sequence, sequential t.
//
// v8: DOUBLE THE READ-CARRYING WAVES PER CU (8 waves/CU on all 256 CUs).
//   Evidence ledger: per-wave READ rate is ~1.6-1.9 GB/s across every
//   structure (scalar loads v4, 1KB DMA v6b, any depth) -> cap is per-wave
//   line-fill concurrency x latency, not DRAM/granule/depth. v7 (4 waves/
//   SIMD on 64 CUs): per-CU 13->19 GB/s but 4x fewer CUs = net loss. Fill
//   (store-only) does 26 GB/s/CU: stores don't stall. Every prior variant
//   had exactly 4 read-waves/CU. Here: 256 blocks x 512 threads =
//   4 compute waves + 4 loader waves per CU, ALL issuing global reads:
//   - compute waves: even 16-step chunks into registers (v4 depth-1
//     prefetch) + TE float4, exact reference arithmetic, nt scalar stores.
//   - loader waves: odd chunks into a 2-slot LDS ring via global_load_lds
//     dwordx4 (1KB/instr; wave lw stages rows 4lw..4lw+3), issued one
//     32-step round ahead, own s_waitcnt vmcnt(0), then raw s_barrier.
//   Compute waves synchronize with RAW s_barrier only (__syncthreads would
//   vmcnt(0)-drain their register prefetch every round = v1's serializer).
//   LDS slot r&1 holds chunk 2r+1, completed before the barrier that opens
//   round r (loader's vmcnt(0) precedes it). Ring depth 2 is safe: slot
//   (r+1)&1 overwritten in round r was consumed in round r-1.
//   LDS: 2*16*256*4 = 32 KiB. VGPR ~120 -> fine at 2 waves/SIMD.

#define T_STEPS 512
#define BATCH   64
#define NNEUR   1024
#define BN      (BATCH * NNEUR)
#define UC      16                   // chunk (t-steps)
#define RT      32                   // t per round = 2 chunks (even+odd)
#define NR      (T_STEPS / RT)       // 16 rounds
#define CT      256                  // compute threads per block
#define BT      512                  // + 256 loader threads

__global__ __launch_bounds__(BT) void telif_kernel(
    const float* __restrict__ tx, const float* __restrict__ TE,
    float* __restrict__ out)
{
    // Reference is validated against fp32 elementwise ops with a hard
    // (v > th) threshold: forbid FMA contraction so rounding matches exactly.
#pragma clang fp contract(off)

    __shared__ float buf[2][UC][CT];           // odd-chunk ring, 32 KiB

    const int tid = threadIdx.x;
    const int blockBase = blockIdx.x * CT;     // first flat (b*N+n) index

    if (tid >= CT) {
        // -------------- loader waves (threads 256..511) --------------
        const int t2 = tid - CT;
        const int lw = t2 >> 6;                // loader wave 0..3
        const int ln = t2 & 63;
        // One dwordx4 DMA per t-row: 64 lanes x 16 B = the block's whole
        // 1 KB span of that row. LDS dest uniform + lane*16 (linear).
        const float* gld = tx + blockBase + ln * 4;

        auto issue_chunk = [&](int k, int slot) {
#pragma unroll
            for (int j = 0; j < 4; ++j) {      // wave lw stages rows 4lw..4lw+3
                const int row = 4 * lw + j;
                const float* g = gld + (size_t)(k * UC + row) * BN;
                __builtin_amdgcn_global_load_lds(
                    (const __attribute__((address_space(1))) void*)g,
                    (__attribute__((address_space(3))) void*)&buf[slot][row][0],
                    16, 0, 0);
            }
        };

        // Prologue: chunk 1 -> slot 0, complete before the opening barrier.
        issue_chunk(1, 0);
        asm volatile("s_waitcnt vmcnt(0)" ::: "memory");
        __builtin_amdgcn_s_barrier();          // opens round 0

        for (int r = 0; r < NR; ++r) {
            const int k = 2 * r + 3;           // odd chunk for round r+1
            if (k < 2 * NR) {
                issue_chunk(k, (r + 1) & 1);
                asm volatile("s_waitcnt vmcnt(0)" ::: "memory");
            }
            __builtin_amdgcn_s_barrier();      // closes round r
        }
        return;
    }

    // -------------- compute waves (threads 0..255) --------------
    const int flat = blockBase + tid;          // b*N + n
    const int n = flat & (NNEUR - 1);
    const float* txp = tx + flat;              // stride BN along t
    const float* tep = TE + n * T_STEPS;       // contiguous along t
    float*       outp = out + flat;

    float v  = 0.0f;   // REST
    float y  = 0.0f;
    float th = 0.3f;   // THRESHOLD

    float xc[UC], xn[UC];                      // even-chunk register buffers
    float tc[RT], tn[RT];                      // TE for the 32-step round

    // Prefetch round 0: even chunk 0 + TE t=0..31.
#pragma unroll
    for (int u = 0; u < UC; ++u)
        xc[u] = txp[(size_t)u * BN];
#pragma unroll
    for (int u = 0; u < RT; u += 4) {
        float4 f = *reinterpret_cast<const float4*>(tep + u);
        tc[u] = f.x; tc[u + 1] = f.y; tc[u + 2] = f.z; tc[u + 3] = f.w;
    }
    __builtin_amdgcn_s_barrier();              // opens round 0 (slot 0 ready)

#pragma unroll 1
    for (int r = 0; r < NR; ++r) {
        const int t0 = r * RT;

        // Prefetch next round: even chunk 2r+2 regs + TE. Issued before this
        // round's stores, so the rotate's counted wait never drains stores.
        if (r + 1 < NR) {
#pragma unroll
            for (int u = 0; u < UC; ++u)
                xn[u] = txp[(size_t)(t0 + RT + u) * BN];
#pragma unroll
            for (int u = 0; u < RT; u += 4) {
                float4 f = *reinterpret_cast<const float4*>(tep + t0 + RT + u);
                tn[u] = f.x; tn[u+1] = f.y; tn[u+2] = f.z; tn[u+3] = f.w;
            }
        }

        // Even chunk (t0..t0+15) from registers. Exact reference op order:
        //   th = th + v*te - (th - THRESHOLD)*BETA
        //   v  = v*DECAY*(1-y) + x
        //   y  = (v > th)
#pragma unroll
        for (int u = 0; u < UC; ++u) {
            float a    = v * tc[u];
            float bsum = th + a;
            float c    = th - 0.3f;
            float d    = c * 0.02f;
            th = bsum - d;
            float e  = v * 0.2f;
            float f1 = 1.0f - y;
            float g  = e * f1;
            v = g + xc[u];
            y = (v > th) ? 1.0f : 0.0f;
            __builtin_nontemporal_store(y, outp + (size_t)(t0 + u) * BN);
        }

        // Odd chunk (t0+16..t0+31) from LDS slot r&1 (chunk 2r+1, complete
        // before this round's opening barrier). tid column: 2 lanes/bank,
        // conflict-free; lgkmcnt handled by compiler at use.
        const float* xs = &buf[r & 1][0][tid];
#pragma unroll
        for (int u = 0; u < UC; ++u) {
            float x    = xs[(size_t)u * CT];
            float a    = v * tc[UC + u];
            float bsum = th + a;
            float c    = th - 0.3f;
            float d    = c * 0.02f;
            th = bsum - d;
            float e  = v * 0.2f;
            float f1 = 1.0f - y;
            float g  = e * f1;
            v = g + x;
            y = (v > th) ? 1.0f : 0.0f;
            __builtin_nontemporal_store(y, outp + (size_t)(t0 + UC + u) * BN);
        }

        // Rotate register buffers (compiler emits precise counted waits).
#pragma unroll
        for (int u = 0; u < UC; ++u) xc[u] = xn[u];
#pragma unroll
        for (int u = 0; u < RT; ++u) tc[u] = tn[u];

        __builtin_amdgcn_s_barrier();          // closes round r
    }
}

extern "C" void kernel_launch(void* const* d_in, const int* in_sizes, int n_in,
                              void* d_out, int out_size, void* d_ws, size_t ws_size,
                              hipStream_t stream) {
    const float* tx = (const float*)d_in[0];  // [T, B, N]
    const float* TE = (const float*)d_in[1];  // [N, T]
    float* out = (float*)d_out;               // [T, B, N]
    telif_kernel<<<BN / CT, BT, 0, stream>>>(tx, TE, out);
}